// Round 6
// baseline (2743.513 us; speedup 1.0000x reference)
//
// Round 6: attention rewrite. R5 evidence: attn = 1113 µs at VALUBusy 17%,
// Occupancy 6.7% — LDS-pipe-bound (16 ds_read_b128 vs 128 FMA per key, 4 waves
// sharing one LDS pipe) and only 256 blocks for 256 CUs. Fix: no LDS (uniform
// global loads from L1/L2), 4 threads per q-row (d-quarters) -> 4096 waves,
// shfl_xor quad reduce, 4-key chunks with conditional rescale.
// GEMMs intentionally unchanged (fp32, ~115 µs each) — single-unknown rounds.
#include <hip/hip_runtime.h>
#include <math.h>

namespace {

constexpr int S_LEN = 2048;
constexpr int NH    = 16;
constexpr int DH    = 64;
constexpr int DE    = 1024;
constexpr float ATT_SCALE = 0.125f;  // 64^-0.5

// C[m,n] = sum_k A[m,k] * W[n,k]   (torch Linear: y = x @ W.T)
// mode 0: C[m*N+n]   mode 1: scatter to [B, H, S, Dh] (m = b*S+s, n = h*DH+dh)
__global__ __launch_bounds__(256) void gemm_nt_kernel(
    const float* __restrict__ A, const float* __restrict__ W,
    float* __restrict__ C, int M, int N, int K, int mode)
{
  constexpr int BK = 16;
  constexpr int P  = 68;          // pad: keeps ds_write 2-way max, reads 16B-aligned
  __shared__ float As[BK][P];     // stored k-major: As[k][row]
  __shared__ float Bs[BK][P];

  const int m0  = blockIdx.x * 64;
  const int n0  = blockIdx.y * 64;
  const int tid = threadIdx.x;
  const int ty  = tid >> 4;       // 0..15 -> 4 output rows
  const int tx  = tid & 15;       // 0..15 -> 4 output cols
  const int lrow = tid >> 2;      // 0..63  (staging row)
  const int lk   = (tid & 3) << 2;// 0,4,8,12 (staging k offset)

  float c[4][4] = {};

  const float* Arow = A + (size_t)(m0 + lrow) * K + lk;
  const float* Wrow = W + (size_t)(n0 + lrow) * K + lk;

  for (int k0 = 0; k0 < K; k0 += BK) {
    const float4 av = *reinterpret_cast<const float4*>(Arow + k0);
    const float4 wv = *reinterpret_cast<const float4*>(Wrow + k0);
    __syncthreads();
    As[lk+0][lrow] = av.x; As[lk+1][lrow] = av.y;
    As[lk+2][lrow] = av.z; As[lk+3][lrow] = av.w;
    Bs[lk+0][lrow] = wv.x; Bs[lk+1][lrow] = wv.y;
    Bs[lk+2][lrow] = wv.z; Bs[lk+3][lrow] = wv.w;
    __syncthreads();
#pragma unroll
    for (int k = 0; k < BK; ++k) {
      const float4 a = *reinterpret_cast<const float4*>(&As[k][ty << 2]);
      const float4 b = *reinterpret_cast<const float4*>(&Bs[k][tx << 2]);
      c[0][0] = fmaf(a.x, b.x, c[0][0]); c[0][1] = fmaf(a.x, b.y, c[0][1]);
      c[0][2] = fmaf(a.x, b.z, c[0][2]); c[0][3] = fmaf(a.x, b.w, c[0][3]);
      c[1][0] = fmaf(a.y, b.x, c[1][0]); c[1][1] = fmaf(a.y, b.y, c[1][1]);
      c[1][2] = fmaf(a.y, b.z, c[1][2]); c[1][3] = fmaf(a.y, b.w, c[1][3]);
      c[2][0] = fmaf(a.z, b.x, c[2][0]); c[2][1] = fmaf(a.z, b.y, c[2][1]);
      c[2][2] = fmaf(a.z, b.z, c[2][2]); c[2][3] = fmaf(a.z, b.w, c[2][3]);
      c[3][0] = fmaf(a.w, b.x, c[3][0]); c[3][1] = fmaf(a.w, b.y, c[3][1]);
      c[3][2] = fmaf(a.w, b.z, c[3][2]); c[3][3] = fmaf(a.w, b.w, c[3][3]);
    }
  }

#pragma unroll
  for (int i = 0; i < 4; ++i) {
    const int row = m0 + (ty << 2) + i;
    const int col = n0 + (tx << 2);
    const float4 v = make_float4(c[i][0], c[i][1], c[i][2], c[i][3]);
    if (mode == 0) {
      *reinterpret_cast<float4*>(&C[(size_t)row * N + col]) = v;
    } else {
      const int b  = row >> 11;            // row / S_LEN
      const int sq = row & (S_LEN - 1);
      const int h  = col >> 6;             // col / DH
      const int dh = col & (DH - 1);
      *reinterpret_cast<float4*>(
          &C[(((size_t)(b * NH + h)) * S_LEN + sq) * DH + dh]) = v;
    }
  }
}

// Flash attention v2: 4 threads per query row, each owns a 16-wide d-quarter.
// No LDS: quad lanes read identical K/V addresses (hw broadcast, L1/L2-served),
// freeing the LDS pipe; QK dot reduced across the quad via shfl_xor.
// Q,K,V in [B,H,S,Dh]; O written as [B,S,DE] (head-concat) for the out-proj.
__global__ __launch_bounds__(256, 4) void attn_kernel(
    const float* __restrict__ Qp, const float* __restrict__ Kp,
    const float* __restrict__ Vp, float* __restrict__ Op)
{
  const int bid    = blockIdx.x;
  const int bh     = bid & 31;        // b*NH+h ; consecutive blocks hit
  const int stile  = bid >> 5;        // different bh; CU-stride-256 blocks
                                      // span work tiers (causal balance)
  const int tid    = threadIdx.x;
  const int s0w    = stile * 64 + (tid >> 6) * 16;   // wave's first row
  const int row    = s0w + ((tid & 63) >> 2);        // this thread's q row
  const int dq     = (tid & 3) << 4;                 // d-quarter offset
  const size_t base = (size_t)bh * S_LEN * DH;

  // q quarter (16 floats) in registers
  float4 q0, q1, q2, q3;
  {
    const float4* Qr = reinterpret_cast<const float4*>(
        Qp + base + (size_t)row * DH + dq);
    q0 = Qr[0]; q1 = Qr[1]; q2 = Qr[2]; q3 = Qr[3];
  }

  float o[16] = {0.f};
  float m = -INFINITY, l = 0.f;

  const int nkeys = s0w + 16;          // wave-uniform causal bound
  for (int kk = 0; kk < nkeys; kk += 4) {
    float sc[4];
#pragma unroll
    for (int j = 0; j < 4; ++j) {
      const int key = kk + j;
      const float4* Kr = reinterpret_cast<const float4*>(
          Kp + base + (size_t)key * DH + dq);
      const float4 k0 = Kr[0], k1 = Kr[1], k2 = Kr[2], k3 = Kr[3];
      float a0 = q0.x * k0.x, a1 = q0.y * k0.y;
      a0 = fmaf(q0.z, k0.z, a0); a1 = fmaf(q0.w, k0.w, a1);
      a0 = fmaf(q1.x, k1.x, a0); a1 = fmaf(q1.y, k1.y, a1);
      a0 = fmaf(q1.z, k1.z, a0); a1 = fmaf(q1.w, k1.w, a1);
      a0 = fmaf(q2.x, k2.x, a0); a1 = fmaf(q2.y, k2.y, a1);
      a0 = fmaf(q2.z, k2.z, a0); a1 = fmaf(q2.w, k2.w, a1);
      a0 = fmaf(q3.x, k3.x, a0); a1 = fmaf(q3.y, k3.y, a1);
      a0 = fmaf(q3.z, k3.z, a0); a1 = fmaf(q3.w, k3.w, a1);
      float s = a0 + a1;
      s += __shfl_xor(s, 1, 64);       // quad reduce (lanes 4r..4r+3)
      s += __shfl_xor(s, 2, 64);
      s *= ATT_SCALE;
      sc[j] = (key <= row) ? s : -INFINITY;
    }

    const float smax = fmaxf(fmaxf(sc[0], sc[1]), fmaxf(sc[2], sc[3]));
    const float newm = fmaxf(m, smax);
    if (__any(newm > m)) {             // wave-uniform skip of rescale
      const float resc = __expf(m - newm);   // 0 on first chunk (m=-inf)
      l *= resc;
#pragma unroll
      for (int d = 0; d < 16; ++d) o[d] *= resc;
      m = newm;
    }

    float p[4];
#pragma unroll
    for (int j = 0; j < 4; ++j) p[j] = __expf(sc[j] - m);  // masked -> 0
    l += (p[0] + p[1]) + (p[2] + p[3]);

#pragma unroll
    for (int j = 0; j < 4; ++j) {
      const float4* Vr = reinterpret_cast<const float4*>(
          Vp + base + (size_t)(kk + j) * DH + dq);
      const float4 v0 = Vr[0], v1 = Vr[1], v2 = Vr[2], v3 = Vr[3];
      const float pj = p[j];
      o[0]  = fmaf(pj, v0.x, o[0]);  o[1]  = fmaf(pj, v0.y, o[1]);
      o[2]  = fmaf(pj, v0.z, o[2]);  o[3]  = fmaf(pj, v0.w, o[3]);
      o[4]  = fmaf(pj, v1.x, o[4]);  o[5]  = fmaf(pj, v1.y, o[5]);
      o[6]  = fmaf(pj, v1.z, o[6]);  o[7]  = fmaf(pj, v1.w, o[7]);
      o[8]  = fmaf(pj, v2.x, o[8]);  o[9]  = fmaf(pj, v2.y, o[9]);
      o[10] = fmaf(pj, v2.z, o[10]); o[11] = fmaf(pj, v2.w, o[11]);
      o[12] = fmaf(pj, v3.x, o[12]); o[13] = fmaf(pj, v3.y, o[13]);
      o[14] = fmaf(pj, v3.z, o[14]); o[15] = fmaf(pj, v3.w, o[15]);
    }
  }

  const float inv = 1.0f / l;
  const int b = bh >> 4, h = bh & 15;
  float* Orow = Op + ((size_t)b * S_LEN + row) * DE + h * DH + dq;
  float4* O4 = reinterpret_cast<float4*>(Orow);
  O4[0] = make_float4(o[0]  * inv, o[1]  * inv, o[2]  * inv, o[3]  * inv);
  O4[1] = make_float4(o[4]  * inv, o[5]  * inv, o[6]  * inv, o[7]  * inv);
  O4[2] = make_float4(o[8]  * inv, o[9]  * inv, o[10] * inv, o[11] * inv);
  O4[3] = make_float4(o[12] * inv, o[13] * inv, o[14] * inv, o[15] * inv);
}

}  // namespace

extern "C" void kernel_launch(void* const* d_in, const int* in_sizes, int n_in,
                              void* d_out, int out_size, void* d_ws, size_t ws_size,
                              hipStream_t stream) {
  const float* x  = (const float*)d_in[0];
  const float* Wq = (const float*)d_in[1];
  const float* Wk = (const float*)d_in[2];
  const float* Wv = (const float*)d_in[3];
  const float* Wo = (const float*)d_in[4];
  float* out = (float*)d_out;

  float* ws = (float*)d_ws;
  const size_t per = (size_t)2 * NH * S_LEN * DH;  // 4,194,304 floats per tensor
  const size_t need_bytes = 4 * per * sizeof(float);  // Q,K,V,O = 64 MiB
  if (ws_size < need_bytes) return;  // never scribble past the workspace

  float* Qw = ws;
  float* Kw = ws + per;
  float* Vw = ws + 2 * per;
  float* Ow = ws + 3 * per;

  const int M = 2 * S_LEN;  // 4096 token rows
  dim3 gg(M / 64, DE / 64);
  dim3 bb(256);

  gemm_nt_kernel<<<gg, bb, 0, stream>>>(x, Wq, Qw, M, DE, DE, 1);
  gemm_nt_kernel<<<gg, bb, 0, stream>>>(x, Wk, Kw, M, DE, DE, 1);
  gemm_nt_kernel<<<gg, bb, 0, stream>>>(x, Wv, Vw, M, DE, DE, 1);

  // 4 threads/row * 65536 rows / 256 = 1024 blocks (4 per CU, 16 waves/CU)
  attn_kernel<<<dim3(1024), bb, 0, stream>>>(Qw, Kw, Vw, Ow);

  gemm_nt_kernel<<<gg, bb, 0, stream>>>(Ow, Wo, out, M, DE, DE, 0);
}

// Round 8
// 758.613 us; speedup vs baseline: 3.6165x; 3.6165x over previous
//
// Round 8 resubmission: R7 never reached hardware (GPUAcquisitionTimeout).
// Source re-audited offline (QK^T swap layout, P->PV fragment handoff,
// ds_bpermute col->row crossing, causal coverage, alignment): no defects
// found; logic unchanged.
// R6 evidence basis: fp32 VALU attention is structurally bound (~1 FMA per
// loaded element) -> matrix cores. Swapped QK^T (D[key][q], m89 layout) makes
// P the exact A-fragment of 16x16x16bf16_1k. V stored pre-transposed bf16 by
// the V-projection epilogue. GEMMs stay fp32 compute.
#include <hip/hip_runtime.h>
#include <math.h>

namespace {

constexpr int S_LEN = 2048;
constexpr int NH    = 16;
constexpr int DH    = 64;
constexpr int DE    = 1024;
constexpr float ATT_SCALE = 0.125f;  // 64^-0.5

typedef __attribute__((ext_vector_type(4))) float f32x4;
typedef __attribute__((ext_vector_type(8))) short s16x8;
typedef __attribute__((ext_vector_type(4))) short s16x4;

__device__ __forceinline__ short f2bf(float f) {
  unsigned int u = __float_as_uint(f);
  u += 0x7fffu + ((u >> 16) & 1u);   // RNE to bf16
  return (short)(u >> 16);
}

// C[m,n] = sum_k A[m,k] * W[n,k]   (torch Linear: y = x @ W.T)
// mode 0: fp32 C[m*N+n]
// mode 1: bf16 scatter to [B, H, S, Dh]      (Q, K)
// mode 2: bf16 scatter to [B, H, Dh, S] (V^T for the PV MFMA B-fragment)
__global__ __launch_bounds__(256) void gemm_nt_kernel(
    const float* __restrict__ A, const float* __restrict__ W,
    void* __restrict__ Cv, int M, int N, int K, int mode)
{
  constexpr int BK = 16;
  constexpr int P  = 68;
  __shared__ float As[BK][P];     // k-major: As[k][row]
  __shared__ float Bs[BK][P];

  const int m0  = blockIdx.x * 64;
  const int n0  = blockIdx.y * 64;
  const int tid = threadIdx.x;
  const int ty  = tid >> 4;
  const int tx  = tid & 15;
  const int lrow = tid >> 2;
  const int lk   = (tid & 3) << 2;

  float c[4][4] = {};

  const float* Arow = A + (size_t)(m0 + lrow) * K + lk;
  const float* Wrow = W + (size_t)(n0 + lrow) * K + lk;

  for (int k0 = 0; k0 < K; k0 += BK) {
    const float4 av = *reinterpret_cast<const float4*>(Arow + k0);
    const float4 wv = *reinterpret_cast<const float4*>(Wrow + k0);
    __syncthreads();
    As[lk+0][lrow] = av.x; As[lk+1][lrow] = av.y;
    As[lk+2][lrow] = av.z; As[lk+3][lrow] = av.w;
    Bs[lk+0][lrow] = wv.x; Bs[lk+1][lrow] = wv.y;
    Bs[lk+2][lrow] = wv.z; Bs[lk+3][lrow] = wv.w;
    __syncthreads();
#pragma unroll
    for (int k = 0; k < BK; ++k) {
      const float4 a = *reinterpret_cast<const float4*>(&As[k][ty << 2]);
      const float4 b = *reinterpret_cast<const float4*>(&Bs[k][tx << 2]);
      c[0][0] = fmaf(a.x, b.x, c[0][0]); c[0][1] = fmaf(a.x, b.y, c[0][1]);
      c[0][2] = fmaf(a.x, b.z, c[0][2]); c[0][3] = fmaf(a.x, b.w, c[0][3]);
      c[1][0] = fmaf(a.y, b.x, c[1][0]); c[1][1] = fmaf(a.y, b.y, c[1][1]);
      c[1][2] = fmaf(a.y, b.z, c[1][2]); c[1][3] = fmaf(a.y, b.w, c[1][3]);
      c[2][0] = fmaf(a.z, b.x, c[2][0]); c[2][1] = fmaf(a.z, b.y, c[2][1]);
      c[2][2] = fmaf(a.z, b.z, c[2][2]); c[2][3] = fmaf(a.z, b.w, c[2][3]);
      c[3][0] = fmaf(a.w, b.x, c[3][0]); c[3][1] = fmaf(a.w, b.y, c[3][1]);
      c[3][2] = fmaf(a.w, b.z, c[3][2]); c[3][3] = fmaf(a.w, b.w, c[3][3]);
    }
  }

  const int row0 = m0 + (ty << 2);
  const int col0 = n0 + (tx << 2);
  if (mode == 0) {
    float* C = (float*)Cv;
#pragma unroll
    for (int i = 0; i < 4; ++i) {
      *reinterpret_cast<float4*>(&C[(size_t)(row0 + i) * N + col0]) =
          make_float4(c[i][0], c[i][1], c[i][2], c[i][3]);
    }
  } else if (mode == 1) {
    short* C = (short*)Cv;
    const int h = col0 >> 6, dh = col0 & 63;
#pragma unroll
    for (int i = 0; i < 4; ++i) {
      const int row = row0 + i;
      const int b = row >> 11, sq = row & (S_LEN - 1);
      s16x4 v;
      v[0] = f2bf(c[i][0]); v[1] = f2bf(c[i][1]);
      v[2] = f2bf(c[i][2]); v[3] = f2bf(c[i][3]);
      *reinterpret_cast<s16x4*>(
          &C[(((size_t)(b * NH + h)) * S_LEN + sq) * DH + dh]) = v;
    }
  } else {  // mode 2: V^T [B,H,Dh,S]
    short* C = (short*)Cv;
    const int h = col0 >> 6;
    const int b = row0 >> 11, sq0 = row0 & (S_LEN - 1);
#pragma unroll
    for (int j = 0; j < 4; ++j) {
      const int dh = (col0 + j) & 63;
      s16x4 v;
      v[0] = f2bf(c[0][j]); v[1] = f2bf(c[1][j]);
      v[2] = f2bf(c[2][j]); v[3] = f2bf(c[3][j]);
      *reinterpret_cast<s16x4*>(
          &C[(((size_t)(b * NH + h)) * DH + dh) * S_LEN + sq0]) = v;
    }
  }
}

// Flash attention, MFMA bf16. One wave = 16 q-rows; block = 4 waves = 64 rows.
// Swapped QK^T: D_s[key][q] via mfma(K_frag, Q_frag) -> col=lane&15=q,
// row=(lane>>4)*4+reg=key (m89-verified C/D layout). P (exp of scores) is then
// directly the A-fragment of mfma_f32_16x16x16bf16_1k (row=lane&15=q,
// k=(lane>>4)*4+j=key). B-fragment = V^T contiguous along keys.
__global__ __launch_bounds__(256) void attn_mfma_kernel(
    const short* __restrict__ Qb, const short* __restrict__ Kb,
    const short* __restrict__ Vt, float* __restrict__ Op)
{
  const int bid  = blockIdx.x;
  const int bh   = bid & 31;          // round-robin bh so same-qblk blocks
  const int qblk = bid >> 5;          // spread across CUs (causal balance)
  const int wave = threadIdx.x >> 6;
  const int lane = threadIdx.x & 63;
  const int g = lane >> 4, cc = lane & 15;
  const int q0 = qblk * 64 + wave * 16;

  const short* Qh = Qb + (size_t)bh * S_LEN * DH;
  const short* Kh = Kb + (size_t)bh * S_LEN * DH;
  const short* Vh = Vt + (size_t)bh * DH * S_LEN;

  // Q fragment (B-operand of QK^T): col=cc -> q0+cc, k=(g*8+j) -> d
  const s16x8 qf0 = *reinterpret_cast<const s16x8*>(
      Qh + (size_t)(q0 + cc) * DH + g * 8);
  const s16x8 qf1 = *reinterpret_cast<const s16x8*>(
      Qh + (size_t)(q0 + cc) * DH + 32 + g * 8);

  f32x4 o0 = {0.f,0.f,0.f,0.f}, o1 = o0, o2 = o0, o3 = o0;
  float m = -INFINITY, l = 0.f;
  const int q = q0 + cc;
  const int nk = (q0 >> 5) + 1;       // 32-key steps covering keys <= q0+15

  for (int kt = 0; kt < nk; ++kt) {
    const int k0 = kt << 5;
    // ---- scores: two 16-key tiles, each 2 MFMAs over d-halves ----
    f32x4 s0 = {0.f,0.f,0.f,0.f}, s1 = s0;
    {
      const short* kp = Kh + (size_t)(k0 + cc) * DH + g * 8;
      const s16x8 ka0 = *reinterpret_cast<const s16x8*>(kp);
      const s16x8 ka1 = *reinterpret_cast<const s16x8*>(kp + 32);
      const s16x8 kb0 = *reinterpret_cast<const s16x8*>(kp + 16 * DH);
      const s16x8 kb1 = *reinterpret_cast<const s16x8*>(kp + 16 * DH + 32);
      s0 = __builtin_amdgcn_mfma_f32_16x16x32_bf16(ka0, qf0, s0, 0, 0, 0);
      s0 = __builtin_amdgcn_mfma_f32_16x16x32_bf16(ka1, qf1, s0, 0, 0, 0);
      s1 = __builtin_amdgcn_mfma_f32_16x16x32_bf16(kb0, qf0, s1, 0, 0, 0);
      s1 = __builtin_amdgcn_mfma_f32_16x16x32_bf16(kb1, qf1, s1, 0, 0, 0);
    }
    // ---- mask + scale (lane reg r holds key=k0+g*4+r / k0+16+g*4+r) ----
    float sc[8];
#pragma unroll
    for (int r = 0; r < 4; ++r) {
      const int key = k0 + g * 4 + r;
      sc[r]     = (key      <= q) ? s0[r] * ATT_SCALE : -INFINITY;
      sc[r + 4] = (key + 16 <= q) ? s1[r] * ATT_SCALE : -INFINITY;
    }
    // ---- online softmax (column reduce across lane groups) ----
    float pm = sc[0];
#pragma unroll
    for (int r = 1; r < 8; ++r) pm = fmaxf(pm, sc[r]);
    pm = fmaxf(pm, __shfl_xor(pm, 16));
    pm = fmaxf(pm, __shfl_xor(pm, 32));
    const float newm = fmaxf(m, pm);
    const float resc = __expf(m - newm);   // 0 on first step (m=-inf)
    m = newm;
    float p[8], ps = 0.f;
#pragma unroll
    for (int r = 0; r < 8; ++r) { p[r] = __expf(sc[r] - m); ps += p[r]; }
    ps += __shfl_xor(ps, 16);
    ps += __shfl_xor(ps, 32);
    l = l * resc + ps;
    // ---- rescale O accumulators (row layout: q = q0+g*4+r) ----
#pragma unroll
    for (int r = 0; r < 4; ++r) {
      const float rr = __int_as_float(__builtin_amdgcn_ds_bpermute(
          (g * 4 + r) * 4, __float_as_int(resc)));
      o0[r] *= rr; o1[r] *= rr; o2[r] *= rr; o3[r] *= rr;
    }
    // ---- P fragments (A-operand of PV, lane-local) ----
    s16x4 pa0, pa1;
#pragma unroll
    for (int r = 0; r < 4; ++r) { pa0[r] = f2bf(p[r]); pa1[r] = f2bf(p[r + 4]); }
    // ---- PV: O[q][d] += P^T V, per 16-wide d block ----
#pragma unroll
    for (int db = 0; db < 4; ++db) {
      const short* vp = Vh + (size_t)(db * 16 + cc) * S_LEN + k0 + g * 4;
      const s16x4 v0 = *reinterpret_cast<const s16x4*>(vp);
      const s16x4 v1 = *reinterpret_cast<const s16x4*>(vp + 16);
      f32x4* od = (db == 0) ? &o0 : (db == 1) ? &o1 : (db == 2) ? &o2 : &o3;
      *od = __builtin_amdgcn_mfma_f32_16x16x16bf16_1k(pa0, v0, *od, 0, 0, 0);
      *od = __builtin_amdgcn_mfma_f32_16x16x16bf16_1k(pa1, v1, *od, 0, 0, 0);
    }
  }

  // ---- epilogue: normalize and store fp32 [B,S,DE] head-concat ----
  const float inv = 1.0f / l;
  const int b = bh >> 4, h = bh & 15;
#pragma unroll
  for (int r = 0; r < 4; ++r) {
    const float ir = __int_as_float(__builtin_amdgcn_ds_bpermute(
        (g * 4 + r) * 4, __float_as_int(inv)));
    float* orow = Op + ((size_t)b * S_LEN + q0 + g * 4 + r) * DE + h * DH + cc;
    orow[0]  = o0[r] * ir;
    orow[16] = o1[r] * ir;
    orow[32] = o2[r] * ir;
    orow[48] = o3[r] * ir;
  }
}

}  // namespace

extern "C" void kernel_launch(void* const* d_in, const int* in_sizes, int n_in,
                              void* d_out, int out_size, void* d_ws, size_t ws_size,
                              hipStream_t stream) {
  const float* x  = (const float*)d_in[0];
  const float* Wq = (const float*)d_in[1];
  const float* Wk = (const float*)d_in[2];
  const float* Wv = (const float*)d_in[3];
  const float* Wo = (const float*)d_in[4];
  float* out = (float*)d_out;

  const size_t per = (size_t)2 * NH * S_LEN * DH;  // 4,194,304 elements/tensor
  // Q,K,V^T bf16 (8 MiB each) + O fp32 (16 MiB) = 40 MiB
  const size_t need_bytes = 3 * per * sizeof(short) + per * sizeof(float);
  if (ws_size < need_bytes) return;  // never scribble past the workspace

  short* Qw = (short*)d_ws;
  short* Kw = Qw + per;
  short* Vt = Kw + per;
  float* Ow = (float*)(Vt + per);

  const int M = 2 * S_LEN;  // 4096 token rows
  dim3 gg(M / 64, DE / 64);
  dim3 bb(256);

  gemm_nt_kernel<<<gg, bb, 0, stream>>>(x, Wq, Qw, M, DE, DE, 1);
  gemm_nt_kernel<<<gg, bb, 0, stream>>>(x, Wk, Kw, M, DE, DE, 1);
  gemm_nt_kernel<<<gg, bb, 0, stream>>>(x, Wv, Vt, M, DE, DE, 2);

  // 32 bh * 32 q-blocks(64 rows, 4 waves) = 1024 blocks
  attn_mfma_kernel<<<dim3(1024), bb, 0, stream>>>(Qw, Kw, Vt, Ow);

  gemm_nt_kernel<<<gg, bb, 0, stream>>>(Ow, Wo, out, M, DE, DE, 0);
}

// Round 9
// 347.574 us; speedup vs baseline: 7.8933x; 2.1826x over previous
//
// Round 9: bf16-MFMA GEMMs. R8 evidence: attn fixed at 218 µs; 4 fp32 GEMMs
// (~460 µs, 61% of 758) now dominate. Port all projections to bf16 MFMA
// (m97 structure: 128x128 tile, BK=64, global_load_lds w16, 2-barrier K-loop,
// XOR swizzle both-sides per rule #21). QKV fused into one N=3072 dispatch.
// Attn kernel logic unchanged (layouts HW-verified in R8); epilogue now bf16.
#include <hip/hip_runtime.h>
#include <math.h>

namespace {

constexpr int S_LEN = 2048;
constexpr int NH    = 16;
constexpr int DH    = 64;
constexpr int DE    = 1024;
constexpr float ATT_SCALE = 0.125f;  // 64^-0.5

typedef __attribute__((ext_vector_type(4))) float f32x4;
typedef __attribute__((ext_vector_type(8))) short s16x8;
typedef __attribute__((ext_vector_type(4))) short s16x4;

__device__ __forceinline__ short f2bf(float f) {
  unsigned int u = __float_as_uint(f);
  u += 0x7fffu + ((u >> 16) & 1u);   // RNE to bf16
  return (short)(u >> 16);
}

#define GLDS16(g, l) __builtin_amdgcn_global_load_lds(                      \
    (const __attribute__((address_space(1))) unsigned int*)(g),             \
    (__attribute__((address_space(3))) unsigned int*)(l), 16, 0, 0)

// Bulk fp32->bf16: x (1M float4) -> xb; Wq/Wk/Wv (256K float4 each) -> wqkv
// stacked [3072][1024]; Wo -> wob.
__global__ __launch_bounds__(256) void cvt_kernel(
    const float* __restrict__ x,  const float* __restrict__ wq,
    const float* __restrict__ wk, const float* __restrict__ wv,
    const float* __restrict__ wo, short* __restrict__ xb,
    short* __restrict__ wqkv,     short* __restrict__ wob)
{
  const int i4 = blockIdx.x * 256 + (int)threadIdx.x;
  const int NX4 = 1 << 20, NW4 = 1 << 18;
  const float4* s4; s16x4* d4; int so, dofs;
  if (i4 < NX4) {
    s4 = (const float4*)x; d4 = (s16x4*)xb; so = i4; dofs = i4;
  } else {
    const int j = i4 - NX4;
    const int w = j >> 18;          // 0..3 -> wq,wk,wv,wo
    const int o = j & (NW4 - 1);
    so = o;
    if (w == 0)      { s4 = (const float4*)wq; d4 = (s16x4*)wqkv; dofs = o; }
    else if (w == 1) { s4 = (const float4*)wk; d4 = (s16x4*)wqkv; dofs = NW4 + o; }
    else if (w == 2) { s4 = (const float4*)wv; d4 = (s16x4*)wqkv; dofs = 2 * NW4 + o; }
    else             { s4 = (const float4*)wo; d4 = (s16x4*)wob;  dofs = o; }
  }
  const float4 v = s4[so];
  s16x4 ov;
  ov[0] = f2bf(v.x); ov[1] = f2bf(v.y); ov[2] = f2bf(v.z); ov[3] = f2bf(v.w);
  d4[dofs] = ov;
}

// bf16 NT-GEMM, C[m,n] = sum_k A[m,k]*B[n,k]. 128x128 tile, BK=64, 4 waves
// (2x2 of 64x64), 16x16x32 MFMA. LDS [128][64] bf16 linear for global_load_lds;
// XOR swizzle cb ^= (row&7)<<4 applied on the pre-swizzled GLOBAL source and on
// the ds_read address (rule #21: both sides, same involution). ds_read_b128
// conflict: lanes r,r+8 share a bank -> 2-way (free, m136).
// MODE 0: fp32 C[M][N].  MODE 1: bf16 QKV scatter (n<1024 Q, <2048 K, else V^T).
template <int MODE>
__global__ __launch_bounds__(256) void gemm_bf16_kernel(
    const short* __restrict__ A, const short* __restrict__ B,
    float* __restrict__ Cf, short* __restrict__ Qd,
    short* __restrict__ Kd, short* __restrict__ Vd,
    int M, int N, int Klen)
{
  __shared__ short As[128 * 64];   // 16 KB
  __shared__ short Bs[128 * 64];   // 16 KB

  const int m0   = blockIdx.x * 128;
  const int n0   = blockIdx.y * 128;
  const int tid  = threadIdx.x;
  const int wave = tid >> 6, lane = tid & 63;
  const int wr = wave >> 1, wc = wave & 1;
  const int g = lane >> 4, cc = lane & 15;
  const int lrow8 = lane >> 3;         // staging: row within 8-row chunk
  const int lcb   = (lane & 7) << 4;   // staging: linear col byte

  f32x4 acc[4][4];
#pragma unroll
  for (int i = 0; i < 4; ++i)
#pragma unroll
    for (int j = 0; j < 4; ++j) acc[i][j] = (f32x4){0.f, 0.f, 0.f, 0.f};

  for (int k0 = 0; k0 < Klen; k0 += 64) {
#pragma unroll
    for (int i = 0; i < 4; ++i) {
      const int rT = wave * 32 + i * 8;            // wave-uniform LDS base row
      const int rL = rT + lrow8;                   // per-lane tile row
      const int cbs = lcb ^ ((rL & 7) << 4);       // pre-swizzled source byte
      GLDS16((const char*)A + (((size_t)(m0 + rL) * Klen + k0) << 1) + cbs,
             &As[rT * 64]);
      GLDS16((const char*)B + (((size_t)(n0 + rL) * Klen + k0) << 1) + cbs,
             &Bs[rT * 64]);
    }
    __syncthreads();
#pragma unroll
    for (int kk = 0; kk < 2; ++kk) {
      s16x8 af[4], bf[4];
#pragma unroll
      for (int mi = 0; mi < 4; ++mi) {
        const int r = wr * 64 + mi * 16 + cc;
        af[mi] = *reinterpret_cast<const s16x8*>(
            (const char*)As + r * 128 + ((kk * 64 + g * 16) ^ ((r & 7) << 4)));
      }
#pragma unroll
      for (int ni = 0; ni < 4; ++ni) {
        const int r = wc * 64 + ni * 16 + cc;
        bf[ni] = *reinterpret_cast<const s16x8*>(
            (const char*)Bs + r * 128 + ((kk * 64 + g * 16) ^ ((r & 7) << 4)));
      }
#pragma unroll
      for (int mi = 0; mi < 4; ++mi)
#pragma unroll
        for (int ni = 0; ni < 4; ++ni)
          acc[mi][ni] = __builtin_amdgcn_mfma_f32_16x16x32_bf16(
              af[mi], bf[ni], acc[mi][ni], 0, 0, 0);
    }
    __syncthreads();
  }

  if (MODE == 0) {
#pragma unroll
    for (int mi = 0; mi < 4; ++mi) {
      const int mg = m0 + wr * 64 + mi * 16 + g * 4;
#pragma unroll
      for (int ni = 0; ni < 4; ++ni) {
        const int ng = n0 + wc * 64 + ni * 16 + cc;
#pragma unroll
        for (int r = 0; r < 4; ++r)
          Cf[(size_t)(mg + r) * N + ng] = acc[mi][ni][r];
      }
    }
  } else {
    const int sect = n0 >> 10;   // uniform per block (128 | 1024)
#pragma unroll
    for (int mi = 0; mi < 4; ++mi) {
      const int mg = m0 + wr * 64 + mi * 16 + g * 4;
#pragma unroll
      for (int ni = 0; ni < 4; ++ni) {
        const int ng = n0 + wc * 64 + ni * 16 + cc;
        const int nn = ng & 1023, h = nn >> 6, dh = nn & 63;
#pragma unroll
        for (int r = 0; r < 4; ++r) {
          const int row = mg + r, b = row >> 11, s = row & (S_LEN - 1);
          const short v = f2bf(acc[mi][ni][r]);
          if (sect == 0)
            Qd[(((size_t)(b * NH + h)) * S_LEN + s) * DH + dh] = v;
          else if (sect == 1)
            Kd[(((size_t)(b * NH + h)) * S_LEN + s) * DH + dh] = v;
          else
            Vd[(((size_t)(b * NH + h)) * DH + dh) * S_LEN + s] = v;
        }
      }
    }
  }
}

// Flash attention, MFMA bf16 (layouts HW-verified in R8). One wave = 16 q-rows.
// Output now bf16 [B,S,DE] (A-matrix of the bf16 out-proj).
__global__ __launch_bounds__(256) void attn_mfma_kernel(
    const short* __restrict__ Qb, const short* __restrict__ Kb,
    const short* __restrict__ Vt, short* __restrict__ Ob)
{
  const int bid  = blockIdx.x;
  const int bh   = bid & 31;
  const int qblk = bid >> 5;
  const int wave = threadIdx.x >> 6;
  const int lane = threadIdx.x & 63;
  const int g = lane >> 4, cc = lane & 15;
  const int q0 = qblk * 64 + wave * 16;

  const short* Qh = Qb + (size_t)bh * S_LEN * DH;
  const short* Kh = Kb + (size_t)bh * S_LEN * DH;
  const short* Vh = Vt + (size_t)bh * DH * S_LEN;

  const s16x8 qf0 = *reinterpret_cast<const s16x8*>(
      Qh + (size_t)(q0 + cc) * DH + g * 8);
  const s16x8 qf1 = *reinterpret_cast<const s16x8*>(
      Qh + (size_t)(q0 + cc) * DH + 32 + g * 8);

  f32x4 o0 = {0.f,0.f,0.f,0.f}, o1 = o0, o2 = o0, o3 = o0;
  float m = -INFINITY, l = 0.f;
  const int q = q0 + cc;
  const int nk = (q0 >> 5) + 1;

  for (int kt = 0; kt < nk; ++kt) {
    const int k0 = kt << 5;
    f32x4 s0 = {0.f,0.f,0.f,0.f}, s1 = s0;
    {
      const short* kp = Kh + (size_t)(k0 + cc) * DH + g * 8;
      const s16x8 ka0 = *reinterpret_cast<const s16x8*>(kp);
      const s16x8 ka1 = *reinterpret_cast<const s16x8*>(kp + 32);
      const s16x8 kb0 = *reinterpret_cast<const s16x8*>(kp + 16 * DH);
      const s16x8 kb1 = *reinterpret_cast<const s16x8*>(kp + 16 * DH + 32);
      s0 = __builtin_amdgcn_mfma_f32_16x16x32_bf16(ka0, qf0, s0, 0, 0, 0);
      s0 = __builtin_amdgcn_mfma_f32_16x16x32_bf16(ka1, qf1, s0, 0, 0, 0);
      s1 = __builtin_amdgcn_mfma_f32_16x16x32_bf16(kb0, qf0, s1, 0, 0, 0);
      s1 = __builtin_amdgcn_mfma_f32_16x16x32_bf16(kb1, qf1, s1, 0, 0, 0);
    }
    float sc[8];
#pragma unroll
    for (int r = 0; r < 4; ++r) {
      const int key = k0 + g * 4 + r;
      sc[r]     = (key      <= q) ? s0[r] * ATT_SCALE : -INFINITY;
      sc[r + 4] = (key + 16 <= q) ? s1[r] * ATT_SCALE : -INFINITY;
    }
    float pm = sc[0];
#pragma unroll
    for (int r = 1; r < 8; ++r) pm = fmaxf(pm, sc[r]);
    pm = fmaxf(pm, __shfl_xor(pm, 16));
    pm = fmaxf(pm, __shfl_xor(pm, 32));
    const float newm = fmaxf(m, pm);
    const float resc = __expf(m - newm);
    m = newm;
    float p[8], ps = 0.f;
#pragma unroll
    for (int r = 0; r < 8; ++r) { p[r] = __expf(sc[r] - m); ps += p[r]; }
    ps += __shfl_xor(ps, 16);
    ps += __shfl_xor(ps, 32);
    l = l * resc + ps;
#pragma unroll
    for (int r = 0; r < 4; ++r) {
      const float rr = __int_as_float(__builtin_amdgcn_ds_bpermute(
          (g * 4 + r) * 4, __float_as_int(resc)));
      o0[r] *= rr; o1[r] *= rr; o2[r] *= rr; o3[r] *= rr;
    }
    s16x4 pa0, pa1;
#pragma unroll
    for (int r = 0; r < 4; ++r) { pa0[r] = f2bf(p[r]); pa1[r] = f2bf(p[r + 4]); }
#pragma unroll
    for (int db = 0; db < 4; ++db) {
      const short* vp = Vh + (size_t)(db * 16 + cc) * S_LEN + k0 + g * 4;
      const s16x4 v0 = *reinterpret_cast<const s16x4*>(vp);
      const s16x4 v1 = *reinterpret_cast<const s16x4*>(vp + 16);
      f32x4* od = (db == 0) ? &o0 : (db == 1) ? &o1 : (db == 2) ? &o2 : &o3;
      *od = __builtin_amdgcn_mfma_f32_16x16x16bf16_1k(pa0, v0, *od, 0, 0, 0);
      *od = __builtin_amdgcn_mfma_f32_16x16x16bf16_1k(pa1, v1, *od, 0, 0, 0);
    }
  }

  const float inv = 1.0f / l;
  const int b = bh >> 4, h = bh & 15;
#pragma unroll
  for (int r = 0; r < 4; ++r) {
    const float ir = __int_as_float(__builtin_amdgcn_ds_bpermute(
        (g * 4 + r) * 4, __float_as_int(inv)));
    short* orow = Ob + ((size_t)b * S_LEN + q0 + g * 4 + r) * DE + h * DH + cc;
    orow[0]  = f2bf(o0[r] * ir);
    orow[16] = f2bf(o1[r] * ir);
    orow[32] = f2bf(o2[r] * ir);
    orow[48] = f2bf(o3[r] * ir);
  }
}

}  // namespace

extern "C" void kernel_launch(void* const* d_in, const int* in_sizes, int n_in,
                              void* d_out, int out_size, void* d_ws, size_t ws_size,
                              hipStream_t stream) {
  const float* x  = (const float*)d_in[0];
  const float* Wq = (const float*)d_in[1];
  const float* Wk = (const float*)d_in[2];
  const float* Wv = (const float*)d_in[3];
  const float* Wo = (const float*)d_in[4];
  float* out = (float*)d_out;

  // ws layout (shorts): xb 4M | wqkv 3M | wob 1M | Q 4M | K 4M | Vt 4M | Ob 4M
  const size_t M1 = 1u << 20;
  const size_t need_bytes = 24 * M1 * sizeof(short);  // 48 MiB
  if (ws_size < need_bytes) return;

  short* xb   = (short*)d_ws;
  short* wqkv = xb + 4 * M1;
  short* wob  = wqkv + 3 * M1;
  short* Qw   = wob + 1 * M1;
  short* Kw   = Qw + 4 * M1;
  short* Vt   = Kw + 4 * M1;
  short* Ob   = Vt + 4 * M1;

  cvt_kernel<<<dim3(8192), dim3(256), 0, stream>>>(
      x, Wq, Wk, Wv, Wo, xb, wqkv, wob);

  gemm_bf16_kernel<1><<<dim3(32, 24), dim3(256), 0, stream>>>(
      xb, wqkv, nullptr, Qw, Kw, Vt, 4096, 3072, 1024);

  attn_mfma_kernel<<<dim3(1024), dim3(256), 0, stream>>>(Qw, Kw, Vt, Ob);

  gemm_bf16_kernel<0><<<dim3(32, 8), dim3(256), 0, stream>>>(
      Ob, wob, out, nullptr, nullptr, nullptr, 4096, 1024, 1024);
}

// Round 15
// 221.170 us; speedup vs baseline: 12.4046x; 1.5715x over previous
//
// Round 15: fix the R14 FAIL (absmax 0.669 vs 0.060). Invariance analysis:
// QK^T/PV are k-permutation invariant, C/D map is m74/m101-verified, reduces
// are direction-symmetric -> the bug must be in the two HW-unverified
// primitives introduced in R10: permlane32_swap direction (asymmetric use in
// P-crossing scrambles key halves -> O(1) error, matches 0.67) and cvt_pk
// operand order. Both replaced with R8-HW-verified building blocks:
// __shfl_xor(.,32) crossing + pure-C bf16 pair packing. Nothing else changed.
#include <hip/hip_runtime.h>
#include <math.h>

namespace {

constexpr int S_LEN = 2048;
constexpr int NH    = 16;
constexpr int DH    = 64;
constexpr int DE    = 1024;
// log2-domain: Q pre-scaled by 0.125/ln(2); scores land as S*0.125/ln2
constexpr float QSC = 0.18033688011112042f;

typedef __attribute__((ext_vector_type(4)))  float f32x4;
typedef __attribute__((ext_vector_type(16))) float f32x16;
typedef __attribute__((ext_vector_type(8)))  short s16x8;
typedef __attribute__((ext_vector_type(4)))  short s16x4;

__device__ __forceinline__ short f2bf(float f) {
  unsigned int u = __float_as_uint(f);
  u += 0x7fffu + ((u >> 16) & 1u);   // RNE to bf16
  return (short)(u >> 16);
}

// Pack two floats to bf16 pair (lo in bits 0-15). Pure C: no operand-order
// ambiguity (replaces v_cvt_pk_bf16_f32 asm).
__device__ __forceinline__ unsigned pk2(float lo, float hi_) {
  return (unsigned)(unsigned short)f2bf(lo) |
         ((unsigned)(unsigned short)f2bf(hi_) << 16);
}

#define GLDS16(g, l) __builtin_amdgcn_global_load_lds(                      \
    (const __attribute__((address_space(1))) unsigned int*)(g),             \
    (__attribute__((address_space(3))) unsigned int*)(l), 16, 0, 0)

// Bulk fp32->bf16 (unchanged from R9).
__global__ __launch_bounds__(256) void cvt_kernel(
    const float* __restrict__ x,  const float* __restrict__ wq,
    const float* __restrict__ wk, const float* __restrict__ wv,
    const float* __restrict__ wo, short* __restrict__ xb,
    short* __restrict__ wqkv,     short* __restrict__ wob)
{
  const int i4 = blockIdx.x * 256 + (int)threadIdx.x;
  const int NX4 = 1 << 20, NW4 = 1 << 18;
  const float4* s4; s16x4* d4; int so, dofs;
  if (i4 < NX4) {
    s4 = (const float4*)x; d4 = (s16x4*)xb; so = i4; dofs = i4;
  } else {
    const int j = i4 - NX4;
    const int w = j >> 18;
    const int o = j & (NW4 - 1);
    so = o;
    if (w == 0)      { s4 = (const float4*)wq; d4 = (s16x4*)wqkv; dofs = o; }
    else if (w == 1) { s4 = (const float4*)wk; d4 = (s16x4*)wqkv; dofs = NW4 + o; }
    else if (w == 2) { s4 = (const float4*)wv; d4 = (s16x4*)wqkv; dofs = 2 * NW4 + o; }
    else             { s4 = (const float4*)wo; d4 = (s16x4*)wob;  dofs = o; }
  }
  const float4 v = s4[so];
  s16x4 ov;
  ov[0] = f2bf(v.x); ov[1] = f2bf(v.y); ov[2] = f2bf(v.z); ov[3] = f2bf(v.w);
  d4[dofs] = ov;
}

// bf16 NT-GEMM (structure HW-verified in R9). MODE 1 pre-scales Q by QSC.
template <int MODE>
__global__ __launch_bounds__(256) void gemm_bf16_kernel(
    const short* __restrict__ A, const short* __restrict__ B,
    float* __restrict__ Cf, short* __restrict__ Qd,
    short* __restrict__ Kd, short* __restrict__ Vd,
    int M, int N, int Klen)
{
  __shared__ short As[128 * 64];
  __shared__ short Bs[128 * 64];

  const int m0   = blockIdx.x * 128;
  const int n0   = blockIdx.y * 128;
  const int tid  = threadIdx.x;
  const int wave = tid >> 6, lane = tid & 63;
  const int wr = wave >> 1, wc = wave & 1;
  const int g = lane >> 4, cc = lane & 15;
  const int lrow8 = lane >> 3;
  const int lcb   = (lane & 7) << 4;

  f32x4 acc[4][4];
#pragma unroll
  for (int i = 0; i < 4; ++i)
#pragma unroll
    for (int j = 0; j < 4; ++j) acc[i][j] = (f32x4){0.f, 0.f, 0.f, 0.f};

  for (int k0 = 0; k0 < Klen; k0 += 64) {
#pragma unroll
    for (int i = 0; i < 4; ++i) {
      const int rT = wave * 32 + i * 8;
      const int rL = rT + lrow8;
      const int cbs = lcb ^ ((rL & 7) << 4);
      GLDS16((const char*)A + (((size_t)(m0 + rL) * Klen + k0) << 1) + cbs,
             &As[rT * 64]);
      GLDS16((const char*)B + (((size_t)(n0 + rL) * Klen + k0) << 1) + cbs,
             &Bs[rT * 64]);
    }
    __syncthreads();
#pragma unroll
    for (int kk = 0; kk < 2; ++kk) {
      s16x8 af[4], bfr[4];
#pragma unroll
      for (int mi = 0; mi < 4; ++mi) {
        const int r = wr * 64 + mi * 16 + cc;
        af[mi] = *reinterpret_cast<const s16x8*>(
            (const char*)As + r * 128 + ((kk * 64 + g * 16) ^ ((r & 7) << 4)));
      }
#pragma unroll
      for (int ni = 0; ni < 4; ++ni) {
        const int r = wc * 64 + ni * 16 + cc;
        bfr[ni] = *reinterpret_cast<const s16x8*>(
            (const char*)Bs + r * 128 + ((kk * 64 + g * 16) ^ ((r & 7) << 4)));
      }
#pragma unroll
      for (int mi = 0; mi < 4; ++mi)
#pragma unroll
        for (int ni = 0; ni < 4; ++ni)
          acc[mi][ni] = __builtin_amdgcn_mfma_f32_16x16x32_bf16(
              af[mi], bfr[ni], acc[mi][ni], 0, 0, 0);
    }
    __syncthreads();
  }

  if (MODE == 0) {
#pragma unroll
    for (int mi = 0; mi < 4; ++mi) {
      const int mg = m0 + wr * 64 + mi * 16 + g * 4;
#pragma unroll
      for (int ni = 0; ni < 4; ++ni) {
        const int ng = n0 + wc * 64 + ni * 16 + cc;
#pragma unroll
        for (int r = 0; r < 4; ++r)
          Cf[(size_t)(mg + r) * N + ng] = acc[mi][ni][r];
      }
    }
  } else {
    const int sect = n0 >> 10;   // 0=Q 1=K 2=V^T (uniform per block)
#pragma unroll
    for (int mi = 0; mi < 4; ++mi) {
      const int mg = m0 + wr * 64 + mi * 16 + g * 4;
#pragma unroll
      for (int ni = 0; ni < 4; ++ni) {
        const int ng = n0 + wc * 64 + ni * 16 + cc;
        const int nn = ng & 1023, h = nn >> 6, dh = nn & 63;
#pragma unroll
        for (int r = 0; r < 4; ++r) {
          const int row = mg + r, b = row >> 11, s = row & (S_LEN - 1);
          const float cv = acc[mi][ni][r];
          if (sect == 0)
            Qd[(((size_t)(b * NH + h)) * S_LEN + s) * DH + dh] = f2bf(cv * QSC);
          else if (sect == 1)
            Kd[(((size_t)(b * NH + h)) * S_LEN + s) * DH + dh] = f2bf(cv);
          else
            Vd[(((size_t)(b * NH + h)) * DH + dh) * S_LEN + s] = f2bf(cv);
        }
      }
    }
  }
}

// One 32-key step for a 32-q wave. Swapped QK^T: S^T[key][q], col=q=lane&31,
// row_r=(r&3)+8*(r>>2)+4*hi (m74/m101-verified). Swapped PV: O^T[d][q], A=V^T
// (row=d), B=P (col=q, k=hi*8+j). All cross-half traffic via __shfl_xor(.,32)
// (R8-HW-verified semantics). Lane (hi,ln) reg r holds P[key=k0+(r&3)+
// 8*(r>>2)+4*hi][q]; word wN pairs regs (2N,2N+1); fN = partner's wN.
// pb0 slots j=0..7 need keys k0+hi*8+j:
//   hi=0: [w0(k0,1), w1(k2,3), f0(k4,5), f1(k6,7)]
//   hi=1: [f2(k8,9), f3(k10,11), w2(k12,13), w3(k14,15)]
// pb1 slots need keys k0+16+hi*8+j:
//   hi=0: [w4(k16,17), w5(k18,19), f4(k20,21), f5(k22,23)]
//   hi=1: [f6(k24,25), f7(k26,27), w6(k28,29), w7(k30,31)]
template <bool MASKED>
__device__ __forceinline__ void attn_step(
    const int k0, const int q, const int ln, const int hi,
    const short* __restrict__ Kh, const short* __restrict__ Vh,
    const s16x8 qf0, const s16x8 qf1, const s16x8 qf2, const s16x8 qf3,
    f32x16& oA, f32x16& oB, float& m, float& l)
{
  f32x16 s;
#pragma unroll
  for (int r = 0; r < 16; ++r) s[r] = 0.f;
  {
    const short* kp = Kh + (size_t)(k0 + ln) * DH + hi * 8;
    const s16x8 ka0 = *(const s16x8*)(kp);
    const s16x8 ka1 = *(const s16x8*)(kp + 16);
    const s16x8 ka2 = *(const s16x8*)(kp + 32);
    const s16x8 ka3 = *(const s16x8*)(kp + 48);
    s = __builtin_amdgcn_mfma_f32_32x32x16_bf16(ka0, qf0, s, 0, 0, 0);
    s = __builtin_amdgcn_mfma_f32_32x32x16_bf16(ka1, qf1, s, 0, 0, 0);
    s = __builtin_amdgcn_mfma_f32_32x32x16_bf16(ka2, qf2, s, 0, 0, 0);
    s = __builtin_amdgcn_mfma_f32_32x32x16_bf16(ka3, qf3, s, 0, 0, 0);
  }
  float sc[16];
#pragma unroll
  for (int r = 0; r < 16; ++r) {
    if (MASKED) {
      const int key = k0 + (r & 3) + 8 * (r >> 2) + 4 * hi;
      sc[r] = (key <= q) ? s[r] : -INFINITY;
    } else {
      sc[r] = s[r];
    }
  }
  // 32-key row max for this q: 16 local + cross-half shfl (R8-verified)
  float pm = fmaxf(sc[0], sc[1]);
#pragma unroll
  for (int r = 2; r < 16; ++r) pm = fmaxf(pm, sc[r]);
  pm = fmaxf(pm, __shfl_xor(pm, 32));
  const float newm = fmaxf(m, pm);
  const float resc = exp2f(m - newm);   // 0 on first step (m=-inf)
  m = newm;
  float p[16], ps = 0.f;
#pragma unroll
  for (int r = 0; r < 16; ++r) { p[r] = exp2f(sc[r] - m); ps += p[r]; }
  ps += __shfl_xor(ps, 32);
  l = l * resc + ps;
#pragma unroll
  for (int r = 0; r < 16; ++r) { oA[r] *= resc; oB[r] *= resc; }

  // P -> PV B-fragments via pure-C pack + shfl crossing (see header comment)
  const unsigned w0 = pk2(p[0],  p[1]),  w1 = pk2(p[2],  p[3]);
  const unsigned w2 = pk2(p[4],  p[5]),  w3 = pk2(p[6],  p[7]);
  const unsigned w4 = pk2(p[8],  p[9]),  w5 = pk2(p[10], p[11]);
  const unsigned w6 = pk2(p[12], p[13]), w7 = pk2(p[14], p[15]);
  const unsigned f0 = __shfl_xor(w0, 32), f1 = __shfl_xor(w1, 32);
  const unsigned f2x = __shfl_xor(w2, 32), f3 = __shfl_xor(w3, 32);
  const unsigned f4 = __shfl_xor(w4, 32), f5 = __shfl_xor(w5, 32);
  const unsigned f6 = __shfl_xor(w6, 32), f7 = __shfl_xor(w7, 32);
  union { unsigned u[4]; s16x8 v; } pb0, pb1;
  pb0.u[0] = hi ? f2x : w0;  pb0.u[1] = hi ? f3 : w1;
  pb0.u[2] = hi ? w2  : f0;  pb0.u[3] = hi ? w3 : f1;
  pb1.u[0] = hi ? f6  : w4;  pb1.u[1] = hi ? f7 : w5;
  pb1.u[2] = hi ? w6  : f4;  pb1.u[3] = hi ? w7 : f5;
  {
    const short* vp = Vh + (size_t)ln * S_LEN + k0 + hi * 8;
    const s16x8 vA0 = *(const s16x8*)(vp);
    const s16x8 vA1 = *(const s16x8*)(vp + 16);
    const s16x8 vB0 = *(const s16x8*)(vp + 32 * S_LEN);
    const s16x8 vB1 = *(const s16x8*)(vp + 32 * S_LEN + 16);
    oA = __builtin_amdgcn_mfma_f32_32x32x16_bf16(vA0, pb0.v, oA, 0, 0, 0);
    oA = __builtin_amdgcn_mfma_f32_32x32x16_bf16(vA1, pb1.v, oA, 0, 0, 0);
    oB = __builtin_amdgcn_mfma_f32_32x32x16_bf16(vB0, pb0.v, oB, 0, 0, 0);
    oB = __builtin_amdgcn_mfma_f32_32x32x16_bf16(vB1, pb1.v, oB, 0, 0, 0);
  }
}

// Wave = 32 q-rows, no LDS, no block sync. Block's 4 waves take qblks
// {j, 63-j, 31-j, 32+j} -> exactly 130 steps per block (uniform).
__global__ __launch_bounds__(256) void attn_mfma_kernel(
    const short* __restrict__ Qb, const short* __restrict__ Kb,
    const short* __restrict__ Vt, short* __restrict__ Ob)
{
  const int bid  = blockIdx.x;
  const int bh   = bid & 31;
  const int j    = bid >> 5;            // 0..15
  const int wid  = threadIdx.x >> 6;
  const int lane = threadIdx.x & 63;
  const int ln = lane & 31, hi = lane >> 5;
  const int qblk = (wid == 0) ? j : (wid == 1) ? 63 - j
                 : (wid == 2) ? 31 - j : 32 + j;
  const int q0 = qblk * 32;
  const int q  = q0 + ln;

  const short* Qh = Qb + (size_t)bh * S_LEN * DH;
  const short* Kh = Kb + (size_t)bh * S_LEN * DH;
  const short* Vh = Vt + (size_t)bh * DH * S_LEN;

  // Q B-fragments: col=q=ln, k=hi*8+jj over four 16-wide d windows
  const short* qp = Qh + (size_t)q * DH + hi * 8;
  const s16x8 qf0 = *(const s16x8*)(qp);
  const s16x8 qf1 = *(const s16x8*)(qp + 16);
  const s16x8 qf2 = *(const s16x8*)(qp + 32);
  const s16x8 qf3 = *(const s16x8*)(qp + 48);

  f32x16 oA, oB;
#pragma unroll
  for (int r = 0; r < 16; ++r) { oA[r] = 0.f; oB[r] = 0.f; }
  float m = -INFINITY, l = 0.f;

  for (int kt = 0; kt < qblk; ++kt)
    attn_step<false>(kt * 32, q, ln, hi, Kh, Vh, qf0, qf1, qf2, qf3,
                     oA, oB, m, l);
  attn_step<true>(qblk * 32, q, ln, hi, Kh, Vh, qf0, qf1, qf2, qf3,
                  oA, oB, m, l);

  // Epilogue: O^T col=q lane-local; rows r -> d=(r&3)+8*(r>>2)+4*hi.
  // Pairs (r, r+1) are consecutive d -> pack via pk2, 16 u32 stores.
  const float inv = 1.0f / l;
  const int b = bh >> 4, h = bh & 15;
  short* orow = Ob + ((size_t)b * S_LEN + q) * DE + h * DH;
#pragma unroll
  for (int r = 0; r < 16; r += 2) {
    const int d = (r & 3) + 8 * (r >> 2) + 4 * hi;
    *(unsigned*)(orow + d)      = pk2(oA[r] * inv, oA[r + 1] * inv);
    *(unsigned*)(orow + 32 + d) = pk2(oB[r] * inv, oB[r + 1] * inv);
  }
}

}  // namespace

extern "C" void kernel_launch(void* const* d_in, const int* in_sizes, int n_in,
                              void* d_out, int out_size, void* d_ws, size_t ws_size,
                              hipStream_t stream) {
  const float* x  = (const float*)d_in[0];
  const float* Wq = (const float*)d_in[1];
  const float* Wk = (const float*)d_in[2];
  const float* Wv = (const float*)d_in[3];
  const float* Wo = (const float*)d_in[4];
  float* out = (float*)d_out;

  const size_t M1 = 1u << 20;
  const size_t need_bytes = 24 * M1 * sizeof(short);  // 48 MiB
  if (ws_size < need_bytes) return;

  short* xb   = (short*)d_ws;
  short* wqkv = xb + 4 * M1;
  short* wob  = wqkv + 3 * M1;
  short* Qw   = wob + 1 * M1;
  short* Kw   = Qw + 4 * M1;
  short* Vt   = Kw + 4 * M1;
  short* Ob   = Vt + 4 * M1;

  cvt_kernel<<<dim3(8192), dim3(256), 0, stream>>>(
      x, Wq, Wk, Wv, Wo, xb, wqkv, wob);

  gemm_bf16_kernel<1><<<dim3(32, 24), dim3(256), 0, stream>>>(
      xb, wqkv, nullptr, Qw, Kw, Vt, 4096, 3072, 1024);

  attn_mfma_kernel<<<dim3(512), dim3(256), 0, stream>>>(Qw, Kw, Vt, Ob);

  gemm_bf16_kernel<0><<<dim3(32, 8), dim3(256), 0, stream>>>(
      Ob, wob, out, nullptr, nullptr, nullptr, 4096, 1024, 1024);
}